// Round 1
// baseline (1586.406 us; speedup 1.0000x reference)
//
#include <hip/hip_runtime.h>

#define WDIM 100
#define HDIM 60

// ---------------- init: zero accumulator, deg = 1 (self loop) ----------------
__global__ __launch_bounds__(256) void k_init(float* __restrict__ acc,
                                              float* __restrict__ deg,
                                              int N, int NW) {
    int i = blockIdx.x * blockDim.x + threadIdx.x;
    int stride = gridDim.x * blockDim.x;
    for (int idx = i; idx < N; idx += stride) deg[idx] = 1.0f;
    for (int idx = i; idx < NW; idx += stride) acc[idx] = 0.0f;
}

// ---------------- degree: deg[dst] += 1 per edge ----------------
__global__ __launch_bounds__(256) void k_deg(const int* __restrict__ dst,
                                             float* __restrict__ deg, int E) {
    int i = blockIdx.x * blockDim.x + threadIdx.x;
    int stride = gridDim.x * blockDim.x;
    for (int e = i; e < E; e += stride)
        atomicAdd(&deg[dst[e]], 1.0f);
}

// ---------------- dinv = rsqrt(deg) (deg >= 1 always) ----------------
__global__ __launch_bounds__(256) void k_dinv(const float* __restrict__ deg,
                                              float* __restrict__ dinv, int N) {
    int i = blockIdx.x * blockDim.x + threadIdx.x;
    int stride = gridDim.x * blockDim.x;
    for (int idx = i; idx < N; idx += stride)
        dinv[idx] = rsqrtf(deg[idx]);
}

// ---------------- xw = x @ gcn_w^T  (gcn_w staged in LDS, padded) ----------------
__global__ __launch_bounds__(256) void k_xw(const float* __restrict__ x,
                                            const float* __restrict__ gw,
                                            float* __restrict__ xw, int N) {
    __shared__ float ws[WDIM * (WDIM + 1)];
    for (int t = threadIdx.x; t < WDIM * WDIM; t += blockDim.x) {
        int r = t / WDIM, c = t - r * WDIM;
        ws[r * (WDIM + 1) + c] = gw[t];
    }
    __syncthreads();
    int total = N * WDIM;
    int stride = gridDim.x * blockDim.x;
    for (int idx = blockIdx.x * blockDim.x + threadIdx.x; idx < total; idx += stride) {
        int n = idx / WDIM;
        int j = idx - n * WDIM;
        const float* __restrict__ xr = x + (size_t)n * WDIM;
        const float* __restrict__ wr = ws + j * (WDIM + 1);
        float s = 0.0f;
#pragma unroll 4
        for (int k = 0; k < WDIM; ++k) s = fmaf(xr[k], wr[k], s);
        xw[idx] = s;
    }
}

// ---------------- scatter: acc[dst] += xw[src] * dinv[src]*dinv[dst] ----------------
__global__ __launch_bounds__(256) void k_scatter(const int* __restrict__ src,
                                                 const int* __restrict__ dst,
                                                 const float* __restrict__ xw,
                                                 const float* __restrict__ dinv,
                                                 float* __restrict__ acc, int E) {
    int total = E * WDIM;                 // 160M < 2^31
    int stride = gridDim.x * blockDim.x;
    for (int idx = blockIdx.x * blockDim.x + threadIdx.x; idx < total; idx += stride) {
        int e = idx / WDIM;
        int j = idx - e * WDIM;
        int s = src[e], d = dst[e];
        float nrm = dinv[s] * dinv[d];
        float v = xw[(size_t)s * WDIM + j] * nrm;
        atomicAdd(&acc[(size_t)d * WDIM + j], v);
    }
}

// ---------------- post: acc = relu(acc + xw*dinv^2 + gcn_b) ----------------
__global__ __launch_bounds__(256) void k_post(float* __restrict__ acc,
                                              const float* __restrict__ xw,
                                              const float* __restrict__ dinv,
                                              const float* __restrict__ gb, int N) {
    int total = N * WDIM;
    int stride = gridDim.x * blockDim.x;
    for (int idx = blockIdx.x * blockDim.x + threadIdx.x; idx < total; idx += stride) {
        int n = idx / WDIM;
        int j = idx - n * WDIM;
        float di = dinv[n];
        float v = acc[idx] + xw[idx] * di * di + gb[j];
        acc[idx] = fmaxf(v, 0.0f);
    }
}

// ---------------- h = tanh(acc @ w1^T + b1)  [N, H] ----------------
__global__ __launch_bounds__(256) void k_h(const float* __restrict__ acc,
                                           const float* __restrict__ w1,
                                           const float* __restrict__ b1,
                                           float* __restrict__ h, int N) {
    __shared__ float w1s[HDIM * (WDIM + 1)];   // 60*101*4 = 24.2 KB
    for (int t = threadIdx.x; t < HDIM * WDIM; t += blockDim.x) {
        int r = t / WDIM, c = t - r * WDIM;
        w1s[r * (WDIM + 1) + c] = w1[t];
    }
    __syncthreads();
    int total = N * HDIM;
    int stride = gridDim.x * blockDim.x;
    for (int idx = blockIdx.x * blockDim.x + threadIdx.x; idx < total; idx += stride) {
        int n = idx / HDIM;
        int j = idx - n * HDIM;
        const float* __restrict__ ar = acc + (size_t)n * WDIM;
        const float* __restrict__ wr = w1s + j * (WDIM + 1);
        float s = b1[j];
#pragma unroll 4
        for (int k = 0; k < WDIM; ++k) s = fmaf(ar[k], wr[k], s);
        h[idx] = tanhf(s);
    }
}

// ---------------- out = tanh(h @ w2^T + b2)  [N, W] ----------------
__global__ __launch_bounds__(256) void k_out(const float* __restrict__ h,
                                             const float* __restrict__ w2,
                                             const float* __restrict__ b2,
                                             float* __restrict__ out, int N) {
    __shared__ float w2s[WDIM * (HDIM + 1)];   // 100*61*4 = 24.4 KB
    for (int t = threadIdx.x; t < WDIM * HDIM; t += blockDim.x) {
        int r = t / HDIM, c = t - r * HDIM;
        w2s[r * (HDIM + 1) + c] = w2[t];
    }
    __syncthreads();
    int total = N * WDIM;
    int stride = gridDim.x * blockDim.x;
    for (int idx = blockIdx.x * blockDim.x + threadIdx.x; idx < total; idx += stride) {
        int n = idx / WDIM;
        int j = idx - n * WDIM;
        const float* __restrict__ hr = h + (size_t)n * HDIM;
        const float* __restrict__ wr = w2s + j * (HDIM + 1);
        float s = b2[j];
#pragma unroll 4
        for (int k = 0; k < HDIM; ++k) s = fmaf(hr[k], wr[k], s);
        out[idx] = tanhf(s);
    }
}

extern "C" void kernel_launch(void* const* d_in, const int* in_sizes, int n_in,
                              void* d_out, int out_size, void* d_ws, size_t ws_size,
                              hipStream_t stream) {
    const float* x   = (const float*)d_in[0];
    const int*   ei  = (const int*)d_in[1];
    const float* gw  = (const float*)d_in[2];
    const float* gb  = (const float*)d_in[3];
    const float* w1  = (const float*)d_in[4];
    const float* b1  = (const float*)d_in[5];
    const float* w2  = (const float*)d_in[6];
    const float* b2  = (const float*)d_in[7];
    float* out = (float*)d_out;

    const int W = in_sizes[3];          // 100
    const int H = in_sizes[5];          // 60
    const int N = in_sizes[0] / W;      // 100000
    const int E = in_sizes[1] / 2;      // 1600000
    (void)W; (void)H;                   // hard-coded as WDIM/HDIM in kernels

    const int* src = ei;
    const int* dst = ei + E;

    // workspace layout
    float* xw   = (float*)d_ws;                       // N*W
    float* acc  = xw   + (size_t)N * WDIM;            // N*W
    float* hbuf = acc  + (size_t)N * WDIM;            // N*H
    float* deg  = hbuf + (size_t)N * HDIM;            // N
    float* dinv = deg  + N;                           // N

    const int B = 256;
    auto blocks = [](long long work, int cap) {
        long long b = (work + 255) / 256;
        return (int)(b < cap ? b : cap);
    };

    k_init<<<blocks((long long)N * WDIM, 65535), B, 0, stream>>>(acc, deg, N, N * WDIM);
    k_deg<<<blocks(E, 65535), B, 0, stream>>>(dst, deg, E);
    k_dinv<<<blocks(N, 65535), B, 0, stream>>>(deg, dinv, N);
    k_xw<<<blocks((long long)N * WDIM, 65535), B, 0, stream>>>(x, gw, xw, N);
    k_scatter<<<8192, B, 0, stream>>>(src, dst, xw, dinv, acc, E);
    k_post<<<blocks((long long)N * WDIM, 65535), B, 0, stream>>>(acc, xw, dinv, gb, N);
    k_h<<<blocks((long long)N * HDIM, 65535), B, 0, stream>>>(acc, w1, b1, hbuf, N);
    k_out<<<blocks((long long)N * WDIM, 65535), B, 0, stream>>>(hbuf, w2, b2, out, N);
}

// Round 2
// 936.356 us; speedup vs baseline: 1.6942x; 1.6942x over previous
//
#include <hip/hip_runtime.h>

#define WDIM 100
#define HDIM 60

// ---------------- zero int counters ----------------
__global__ __launch_bounds__(256) void k_zero(int* __restrict__ cnt, int N) {
    int i = blockIdx.x * blockDim.x + threadIdx.x;
    int stride = gridDim.x * blockDim.x;
    for (int idx = i; idx < N; idx += stride) cnt[idx] = 0;
}

// ---------------- histogram of dst (incoming degree, excl self-loop) ----------------
__global__ __launch_bounds__(256) void k_hist(const int* __restrict__ dst,
                                              int* __restrict__ cnt, int E) {
    int i = blockIdx.x * blockDim.x + threadIdx.x;
    int stride = gridDim.x * blockDim.x;
    for (int e = i; e < E; e += stride)
        atomicAdd(&cnt[dst[e]], 1);
}

// ---------------- scan step 1: per-256-chunk inclusive scan + block sums ----------------
__global__ __launch_bounds__(256) void k_scan1(const int* __restrict__ cnt,
                                               int* __restrict__ scn,
                                               int* __restrict__ bsum, int N) {
    __shared__ int tmp[256];
    int idx = blockIdx.x * 256 + threadIdx.x;
    int v = (idx < N) ? cnt[idx] : 0;
    tmp[threadIdx.x] = v;
    __syncthreads();
    for (int off = 1; off < 256; off <<= 1) {
        int t = (threadIdx.x >= off) ? tmp[threadIdx.x - off] : 0;
        __syncthreads();
        tmp[threadIdx.x] += t;
        __syncthreads();
    }
    if (idx < N) scn[idx] = tmp[threadIdx.x];
    if (threadIdx.x == 255) bsum[blockIdx.x] = tmp[255];
}

// ---------------- scan step 2: single-block exclusive scan of block sums ----------------
__global__ __launch_bounds__(512) void k_scan2(const int* __restrict__ bsum,
                                               int* __restrict__ bscan, int NB) {
    __shared__ int tmp[512];
    int orig = (threadIdx.x < NB) ? bsum[threadIdx.x] : 0;
    tmp[threadIdx.x] = orig;
    __syncthreads();
    for (int off = 1; off < 512; off <<= 1) {
        int t = (threadIdx.x >= off) ? tmp[threadIdx.x - off] : 0;
        __syncthreads();
        tmp[threadIdx.x] += t;
        __syncthreads();
    }
    if (threadIdx.x < NB) bscan[threadIdx.x] = tmp[threadIdx.x] - orig;
}

// ---------------- scan step 3: row_start/cursor = exclusive scan; dinv ----------------
__global__ __launch_bounds__(256) void k_scan3(const int* __restrict__ cnt,
                                               const int* __restrict__ scn,
                                               const int* __restrict__ bscan,
                                               int* __restrict__ row_start,
                                               int* __restrict__ cursor,
                                               float* __restrict__ dinv, int N) {
    int i = blockIdx.x * blockDim.x + threadIdx.x;
    int stride = gridDim.x * blockDim.x;
    for (int idx = i; idx < N; idx += stride) {
        int c = cnt[idx];
        int ex = scn[idx] - c + bscan[idx >> 8];
        row_start[idx] = ex;
        cursor[idx] = ex;
        dinv[idx] = rsqrtf((float)(c + 1));
    }
}

// ---------------- fill CSR edge list: (src, norm) packed 8B ----------------
__global__ __launch_bounds__(256) void k_fill(const int* __restrict__ src,
                                              const int* __restrict__ dst,
                                              const float* __restrict__ dinv,
                                              int* __restrict__ cursor,
                                              int2* __restrict__ e_pk, int E) {
    int i = blockIdx.x * blockDim.x + threadIdx.x;
    int stride = gridDim.x * blockDim.x;
    for (int e = i; e < E; e += stride) {
        int s = src[e], d = dst[e];
        float nrm = dinv[s] * dinv[d];
        int pos = atomicAdd(&cursor[d], 1);
        e_pk[pos] = make_int2(s, __float_as_int(nrm));
    }
}

// ---------------- xw = x @ gcn_w^T  (gcn_w staged in LDS once per block) ----------------
__global__ __launch_bounds__(256) void k_xw(const float* __restrict__ x,
                                            const float* __restrict__ gw,
                                            float* __restrict__ xw, int N) {
    __shared__ float ws[WDIM * (WDIM + 1)];
    for (int t = threadIdx.x; t < WDIM * WDIM; t += blockDim.x) {
        int r = t / WDIM, c = t - r * WDIM;
        ws[r * (WDIM + 1) + c] = gw[t];
    }
    __syncthreads();
    int total = N * WDIM;
    int stride = gridDim.x * blockDim.x;
    for (int idx = blockIdx.x * blockDim.x + threadIdx.x; idx < total; idx += stride) {
        int n = idx / WDIM;
        int j = idx - n * WDIM;
        const float* __restrict__ xr = x + (size_t)n * WDIM;
        const float* __restrict__ wr = ws + j * (WDIM + 1);
        float s = 0.0f;
#pragma unroll 4
        for (int k = 0; k < WDIM; ++k) s = fmaf(xr[k], wr[k], s);
        xw[idx] = s;
    }
}

// ---------------- pull-gather: wave per node, fused self-loop + bias + relu ----------------
__global__ __launch_bounds__(256) void k_gather(const int2* __restrict__ e_pk,
                                                const int* __restrict__ row_start,
                                                const int* __restrict__ cnt,
                                                const float* __restrict__ xw,
                                                const float* __restrict__ dinv,
                                                const float* __restrict__ gb,
                                                float* __restrict__ acc, int N) {
    int wid = (blockIdx.x * blockDim.x + threadIdx.x) >> 6;
    int lane = threadIdx.x & 63;
    if (wid >= N) return;
    int beg = row_start[wid];
    int num = cnt[wid];
    float s0 = 0.0f, s1 = 0.0f;
    for (int k = 0; k < num; ++k) {
        int2 ed = e_pk[beg + k];              // uniform addr -> broadcast
        int sn = ed.x;
        float nrm = __int_as_float(ed.y);
        const float* __restrict__ xr = xw + (size_t)sn * WDIM;
        s0 = fmaf(xr[lane], nrm, s0);
        if (lane < WDIM - 64) s1 = fmaf(xr[64 + lane], nrm, s1);
    }
    float di = dinv[wid];
    float d2 = di * di;
    const float* __restrict__ xn = xw + (size_t)wid * WDIM;
    float* __restrict__ ar = acc + (size_t)wid * WDIM;
    float v0 = fmaf(xn[lane], d2, s0) + gb[lane];
    ar[lane] = fmaxf(v0, 0.0f);
    if (lane < WDIM - 64) {
        float v1 = fmaf(xn[64 + lane], d2, s1) + gb[64 + lane];
        ar[64 + lane] = fmaxf(v1, 0.0f);
    }
}

// ---------------- h = tanh(acc @ w1^T + b1)  [N, H] ----------------
__global__ __launch_bounds__(256) void k_h(const float* __restrict__ acc,
                                           const float* __restrict__ w1,
                                           const float* __restrict__ b1,
                                           float* __restrict__ h, int N) {
    __shared__ float w1s[HDIM * (WDIM + 1)];
    for (int t = threadIdx.x; t < HDIM * WDIM; t += blockDim.x) {
        int r = t / WDIM, c = t - r * WDIM;
        w1s[r * (WDIM + 1) + c] = w1[t];
    }
    __syncthreads();
    int total = N * HDIM;
    int stride = gridDim.x * blockDim.x;
    for (int idx = blockIdx.x * blockDim.x + threadIdx.x; idx < total; idx += stride) {
        int n = idx / HDIM;
        int j = idx - n * HDIM;
        const float* __restrict__ ar = acc + (size_t)n * WDIM;
        const float* __restrict__ wr = w1s + j * (WDIM + 1);
        float s = b1[j];
#pragma unroll 4
        for (int k = 0; k < WDIM; ++k) s = fmaf(ar[k], wr[k], s);
        h[idx] = tanhf(s);
    }
}

// ---------------- out = tanh(h @ w2^T + b2)  [N, W] ----------------
__global__ __launch_bounds__(256) void k_out(const float* __restrict__ h,
                                             const float* __restrict__ w2,
                                             const float* __restrict__ b2,
                                             float* __restrict__ out, int N) {
    __shared__ float w2s[WDIM * (HDIM + 1)];
    for (int t = threadIdx.x; t < WDIM * HDIM; t += blockDim.x) {
        int r = t / HDIM, c = t - r * HDIM;
        w2s[r * (HDIM + 1) + c] = w2[t];
    }
    __syncthreads();
    int total = N * WDIM;
    int stride = gridDim.x * blockDim.x;
    for (int idx = blockIdx.x * blockDim.x + threadIdx.x; idx < total; idx += stride) {
        int n = idx / WDIM;
        int j = idx - n * WDIM;
        const float* __restrict__ hr = h + (size_t)n * HDIM;
        const float* __restrict__ wr = w2s + j * (HDIM + 1);
        float s = b2[j];
#pragma unroll 4
        for (int k = 0; k < HDIM; ++k) s = fmaf(hr[k], wr[k], s);
        out[idx] = tanhf(s);
    }
}

extern "C" void kernel_launch(void* const* d_in, const int* in_sizes, int n_in,
                              void* d_out, int out_size, void* d_ws, size_t ws_size,
                              hipStream_t stream) {
    const float* x   = (const float*)d_in[0];
    const int*   ei  = (const int*)d_in[1];
    const float* gw  = (const float*)d_in[2];
    const float* gb  = (const float*)d_in[3];
    const float* w1  = (const float*)d_in[4];
    const float* b1  = (const float*)d_in[5];
    const float* w2  = (const float*)d_in[6];
    const float* b2  = (const float*)d_in[7];
    float* out = (float*)d_out;

    const int W = in_sizes[3];          // 100
    const int N = in_sizes[0] / W;      // 100000
    const int E = in_sizes[1] / 2;      // 1600000

    const int* src = ei;
    const int* dst = ei + E;

    // ---- workspace layout (floats/ints, 4B each) ----
    // xw: N*W   | acc: N*W | e_pk: E int2 | cnt,scn,row_start,cursor: N int | dinv: N f | bsum,bscan: 512
    float* xw  = (float*)d_ws;                          // N*W
    float* acc = xw + (size_t)N * WDIM;                 // N*W
    int2*  e_pk = (int2*)(acc + (size_t)N * WDIM);      // E int2 (8B each)
    int*   cnt = (int*)(e_pk + E);                      // N
    int*   scn = cnt + N;                               // N
    int*   row_start = scn + N;                         // N
    int*   cursor = row_start + N;                      // N
    float* dinv = (float*)(cursor + N);                 // N
    int*   bsum = (int*)(dinv + N);                     // 512
    int*   bscan = bsum + 512;                          // 512
    float* hbuf = xw;                                   // alias: xw dead after k_gather

    const int B = 256;
    const int NB = (N + 255) / 256;                     // scan chunks (391)
    auto blocks = [](long long work, int cap) {
        long long b = (work + 255) / 256;
        return (int)(b < cap ? b : cap);
    };

    k_zero<<<blocks(N, 2048), B, 0, stream>>>(cnt, N);
    k_hist<<<blocks(E, 2048), B, 0, stream>>>(dst, cnt, E);
    k_scan1<<<NB, B, 0, stream>>>(cnt, scn, bsum, N);
    k_scan2<<<1, 512, 0, stream>>>(bsum, bscan, NB);
    k_scan3<<<blocks(N, 2048), B, 0, stream>>>(cnt, scn, bscan, row_start, cursor, dinv, N);
    k_fill<<<blocks(E, 2048), B, 0, stream>>>(src, dst, dinv, cursor, e_pk, E);
    k_xw<<<1040, B, 0, stream>>>(x, gw, xw, N);
    k_gather<<<(N * 64 + B - 1) / B, B, 0, stream>>>(e_pk, row_start, cnt, xw, dinv, gb, acc, N);
    k_h<<<1024, B, 0, stream>>>(acc, w1, b1, hbuf, N);
    k_out<<<1040, B, 0, stream>>>(hbuf, w2, b2, out, N);
}

// Round 3
// 580.444 us; speedup vs baseline: 2.7331x; 1.6132x over previous
//
#include <hip/hip_runtime.h>

#define WDIM 100
#define HDIM 60

// ---------------- zero int counters ----------------
__global__ __launch_bounds__(256) void k_zero(int* __restrict__ cnt, int N) {
    int i = blockIdx.x * blockDim.x + threadIdx.x;
    int stride = gridDim.x * blockDim.x;
    for (int idx = i; idx < N; idx += stride) cnt[idx] = 0;
}

// ---------------- histogram of dst (incoming degree, excl self-loop) ----------------
__global__ __launch_bounds__(256) void k_hist(const int* __restrict__ dst,
                                              int* __restrict__ cnt, int E) {
    int i = blockIdx.x * blockDim.x + threadIdx.x;
    int stride = gridDim.x * blockDim.x;
    for (int e = i; e < E; e += stride)
        atomicAdd(&cnt[dst[e]], 1);
}

// ---------------- scan step 1 ----------------
__global__ __launch_bounds__(256) void k_scan1(const int* __restrict__ cnt,
                                               int* __restrict__ scn,
                                               int* __restrict__ bsum, int N) {
    __shared__ int tmp[256];
    int idx = blockIdx.x * 256 + threadIdx.x;
    int v = (idx < N) ? cnt[idx] : 0;
    tmp[threadIdx.x] = v;
    __syncthreads();
    for (int off = 1; off < 256; off <<= 1) {
        int t = (threadIdx.x >= off) ? tmp[threadIdx.x - off] : 0;
        __syncthreads();
        tmp[threadIdx.x] += t;
        __syncthreads();
    }
    if (idx < N) scn[idx] = tmp[threadIdx.x];
    if (threadIdx.x == 255) bsum[blockIdx.x] = tmp[255];
}

// ---------------- scan step 2 ----------------
__global__ __launch_bounds__(512) void k_scan2(const int* __restrict__ bsum,
                                               int* __restrict__ bscan, int NB) {
    __shared__ int tmp[512];
    int orig = (threadIdx.x < NB) ? bsum[threadIdx.x] : 0;
    tmp[threadIdx.x] = orig;
    __syncthreads();
    for (int off = 1; off < 512; off <<= 1) {
        int t = (threadIdx.x >= off) ? tmp[threadIdx.x - off] : 0;
        __syncthreads();
        tmp[threadIdx.x] += t;
        __syncthreads();
    }
    if (threadIdx.x < NB) bscan[threadIdx.x] = tmp[threadIdx.x] - orig;
}

// ---------------- scan step 3 ----------------
__global__ __launch_bounds__(256) void k_scan3(const int* __restrict__ cnt,
                                               const int* __restrict__ scn,
                                               const int* __restrict__ bscan,
                                               int* __restrict__ row_start,
                                               int* __restrict__ cursor,
                                               float* __restrict__ dinv, int N) {
    int i = blockIdx.x * blockDim.x + threadIdx.x;
    int stride = gridDim.x * blockDim.x;
    for (int idx = i; idx < N; idx += stride) {
        int c = cnt[idx];
        int ex = scn[idx] - c + bscan[idx >> 8];
        row_start[idx] = ex;
        cursor[idx] = ex;
        dinv[idx] = rsqrtf((float)(c + 1));
    }
}

// ---------------- fill CSR edge list ----------------
__global__ __launch_bounds__(256) void k_fill(const int* __restrict__ src,
                                              const int* __restrict__ dst,
                                              const float* __restrict__ dinv,
                                              int* __restrict__ cursor,
                                              int2* __restrict__ e_pk, int E) {
    int i = blockIdx.x * blockDim.x + threadIdx.x;
    int stride = gridDim.x * blockDim.x;
    for (int e = i; e < E; e += stride) {
        int s = src[e], d = dst[e];
        float nrm = dinv[s] * dinv[d];
        int pos = atomicAdd(&cursor[d], 1);
        e_pk[pos] = make_int2(s, __float_as_int(nrm));
    }
}

// ================= GEMM 1: xw = x @ gcn_w^T  =================
// block 320 = 16 n-groups(4n) x 20 j-groups(5j); tile 64 nodes; reg tile 4x5
__global__ __launch_bounds__(320) void k_xw(const float* __restrict__ x,
                                            const float* __restrict__ gw,
                                            float* __restrict__ xw,
                                            int N, int ntiles) {
    __shared__ float wst[WDIM][104];   // [k][j]  41.6 KB
    __shared__ float xs[WDIM][68];     // [k][n]  27.2 KB
    for (int t = threadIdx.x; t < WDIM * WDIM; t += 320) {
        int j = t / WDIM, k = t - j * WDIM;
        wst[k][j] = gw[t];
    }
    const int jg = threadIdx.x % 20;
    const int ng = threadIdx.x / 20;
    for (int tile = blockIdx.x; tile < ntiles; tile += gridDim.x) {
        int n0 = tile * 64;
        __syncthreads();
        for (int t = threadIdx.x; t < 64 * WDIM; t += 320) {
            int n = t / WDIM, k = t - n * WDIM;
            int gn = n0 + n;
            xs[k][n] = (gn < N) ? x[(size_t)gn * WDIM + k] : 0.0f;
        }
        __syncthreads();
        float a[4][5];
#pragma unroll
        for (int i = 0; i < 4; ++i)
#pragma unroll
            for (int j = 0; j < 5; ++j) a[i][j] = 0.0f;
#pragma unroll 2
        for (int k = 0; k < WDIM; ++k) {
            float4 xv = *(const float4*)&xs[k][4 * ng];
            float w0 = wst[k][5 * jg + 0];
            float w1 = wst[k][5 * jg + 1];
            float w2 = wst[k][5 * jg + 2];
            float w3 = wst[k][5 * jg + 3];
            float w4 = wst[k][5 * jg + 4];
#pragma unroll
            for (int nn = 0; nn < 4; ++nn) {
                float xvv = (&xv.x)[nn];
                a[nn][0] = fmaf(xvv, w0, a[nn][0]);
                a[nn][1] = fmaf(xvv, w1, a[nn][1]);
                a[nn][2] = fmaf(xvv, w2, a[nn][2]);
                a[nn][3] = fmaf(xvv, w3, a[nn][3]);
                a[nn][4] = fmaf(xvv, w4, a[nn][4]);
            }
        }
#pragma unroll
        for (int nn = 0; nn < 4; ++nn) {
            int gn = n0 + 4 * ng + nn;
            if (gn < N) {
                float* __restrict__ o = xw + (size_t)gn * WDIM + 5 * jg;
#pragma unroll
                for (int jj = 0; jj < 5; ++jj) o[jj] = a[nn][jj];
            }
        }
    }
}

// ---------------- pull-gather: wave per node, fused self-loop + bias + relu ----------------
__global__ __launch_bounds__(256) void k_gather(const int2* __restrict__ e_pk,
                                                const int* __restrict__ row_start,
                                                const int* __restrict__ cnt,
                                                const float* __restrict__ xw,
                                                const float* __restrict__ dinv,
                                                const float* __restrict__ gb,
                                                float* __restrict__ acc, int N) {
    int wid = (blockIdx.x * blockDim.x + threadIdx.x) >> 6;
    int lane = threadIdx.x & 63;
    if (wid >= N) return;
    int beg = row_start[wid];
    int num = cnt[wid];
    float s0 = 0.0f, s1 = 0.0f;
    for (int k = 0; k < num; ++k) {
        int2 ed = e_pk[beg + k];
        int sn = ed.x;
        float nrm = __int_as_float(ed.y);
        const float* __restrict__ xr = xw + (size_t)sn * WDIM;
        s0 = fmaf(xr[lane], nrm, s0);
        if (lane < WDIM - 64) s1 = fmaf(xr[64 + lane], nrm, s1);
    }
    float di = dinv[wid];
    float d2 = di * di;
    const float* __restrict__ xn = xw + (size_t)wid * WDIM;
    float* __restrict__ ar = acc + (size_t)wid * WDIM;
    float v0 = fmaf(xn[lane], d2, s0) + gb[lane];
    ar[lane] = fmaxf(v0, 0.0f);
    if (lane < WDIM - 64) {
        float v1 = fmaf(xn[64 + lane], d2, s1) + gb[64 + lane];
        ar[64 + lane] = fmaxf(v1, 0.0f);
    }
}

// ================= GEMM 2: h = tanh(acc @ w1^T + b1) =================
// block 384 = 32 n-groups(4n) x 12 j-groups(5j); tile 128 nodes
__global__ __launch_bounds__(384) void k_h(const float* __restrict__ acc,
                                           const float* __restrict__ w1,
                                           const float* __restrict__ b1,
                                           float* __restrict__ h,
                                           int N, int ntiles) {
    __shared__ float wst[WDIM][64];    // [k][j] j<60  25.6 KB
    __shared__ float xs[WDIM][132];    // [k][n] n<128 52.8 KB
    for (int t = threadIdx.x; t < HDIM * WDIM; t += 384) {
        int j = t / WDIM, k = t - j * WDIM;
        wst[k][j] = w1[t];
    }
    const int jg = threadIdx.x % 12;
    const int ng = threadIdx.x / 12;
    float b[5];
#pragma unroll
    for (int jj = 0; jj < 5; ++jj) b[jj] = b1[5 * jg + jj];
    for (int tile = blockIdx.x; tile < ntiles; tile += gridDim.x) {
        int n0 = tile * 128;
        __syncthreads();
        for (int t = threadIdx.x; t < 128 * WDIM; t += 384) {
            int n = t / WDIM, k = t - n * WDIM;
            int gn = n0 + n;
            xs[k][n] = (gn < N) ? acc[(size_t)gn * WDIM + k] : 0.0f;
        }
        __syncthreads();
        float a[4][5];
#pragma unroll
        for (int i = 0; i < 4; ++i)
#pragma unroll
            for (int j = 0; j < 5; ++j) a[i][j] = b[j];
#pragma unroll 2
        for (int k = 0; k < WDIM; ++k) {
            float4 xv = *(const float4*)&xs[k][4 * ng];
            float w0 = wst[k][5 * jg + 0];
            float w1v = wst[k][5 * jg + 1];
            float w2 = wst[k][5 * jg + 2];
            float w3 = wst[k][5 * jg + 3];
            float w4 = wst[k][5 * jg + 4];
#pragma unroll
            for (int nn = 0; nn < 4; ++nn) {
                float xvv = (&xv.x)[nn];
                a[nn][0] = fmaf(xvv, w0, a[nn][0]);
                a[nn][1] = fmaf(xvv, w1v, a[nn][1]);
                a[nn][2] = fmaf(xvv, w2, a[nn][2]);
                a[nn][3] = fmaf(xvv, w3, a[nn][3]);
                a[nn][4] = fmaf(xvv, w4, a[nn][4]);
            }
        }
#pragma unroll
        for (int nn = 0; nn < 4; ++nn) {
            int gn = n0 + 4 * ng + nn;
            if (gn < N) {
                float* __restrict__ o = h + (size_t)gn * HDIM + 5 * jg;
#pragma unroll
                for (int jj = 0; jj < 5; ++jj) o[jj] = tanhf(a[nn][jj]);
            }
        }
    }
}

// ================= GEMM 3: out = tanh(h @ w2^T + b2) =================
// block 320 = 16 n-groups(4n) x 20 j-groups(5j); tile 64 nodes; K=60
__global__ __launch_bounds__(320) void k_out(const float* __restrict__ h,
                                             const float* __restrict__ w2,
                                             const float* __restrict__ b2,
                                             float* __restrict__ out,
                                             int N, int ntiles) {
    __shared__ float wst[HDIM][104];   // [k][j] k<60  24.96 KB
    __shared__ float xs[HDIM][68];     // [k][n]       16.3 KB
    for (int t = threadIdx.x; t < WDIM * HDIM; t += 320) {
        int j = t / HDIM, k = t - j * HDIM;
        wst[k][j] = w2[t];
    }
    const int jg = threadIdx.x % 20;
    const int ng = threadIdx.x / 20;
    float b[5];
#pragma unroll
    for (int jj = 0; jj < 5; ++jj) b[jj] = b2[5 * jg + jj];
    for (int tile = blockIdx.x; tile < ntiles; tile += gridDim.x) {
        int n0 = tile * 64;
        __syncthreads();
        for (int t = threadIdx.x; t < 64 * HDIM; t += 320) {
            int n = t / HDIM, k = t - n * HDIM;
            int gn = n0 + n;
            xs[k][n] = (gn < N) ? h[(size_t)gn * HDIM + k] : 0.0f;
        }
        __syncthreads();
        float a[4][5];
#pragma unroll
        for (int i = 0; i < 4; ++i)
#pragma unroll
            for (int j = 0; j < 5; ++j) a[i][j] = b[j];
#pragma unroll 2
        for (int k = 0; k < HDIM; ++k) {
            float4 xv = *(const float4*)&xs[k][4 * ng];
            float w0 = wst[k][5 * jg + 0];
            float w1v = wst[k][5 * jg + 1];
            float w2v = wst[k][5 * jg + 2];
            float w3 = wst[k][5 * jg + 3];
            float w4 = wst[k][5 * jg + 4];
#pragma unroll
            for (int nn = 0; nn < 4; ++nn) {
                float xvv = (&xv.x)[nn];
                a[nn][0] = fmaf(xvv, w0, a[nn][0]);
                a[nn][1] = fmaf(xvv, w1v, a[nn][1]);
                a[nn][2] = fmaf(xvv, w2v, a[nn][2]);
                a[nn][3] = fmaf(xvv, w3, a[nn][3]);
                a[nn][4] = fmaf(xvv, w4, a[nn][4]);
            }
        }
#pragma unroll
        for (int nn = 0; nn < 4; ++nn) {
            int gn = n0 + 4 * ng + nn;
            if (gn < N) {
                float* __restrict__ o = out + (size_t)gn * WDIM + 5 * jg;
#pragma unroll
                for (int jj = 0; jj < 5; ++jj) o[jj] = tanhf(a[nn][jj]);
            }
        }
    }
}

extern "C" void kernel_launch(void* const* d_in, const int* in_sizes, int n_in,
                              void* d_out, int out_size, void* d_ws, size_t ws_size,
                              hipStream_t stream) {
    const float* x   = (const float*)d_in[0];
    const int*   ei  = (const int*)d_in[1];
    const float* gw  = (const float*)d_in[2];
    const float* gb  = (const float*)d_in[3];
    const float* w1  = (const float*)d_in[4];
    const float* b1  = (const float*)d_in[5];
    const float* w2  = (const float*)d_in[6];
    const float* b2  = (const float*)d_in[7];
    float* out = (float*)d_out;

    const int W = in_sizes[3];          // 100
    const int N = in_sizes[0] / W;      // 100000
    const int E = in_sizes[1] / 2;      // 1600000

    const int* src = ei;
    const int* dst = ei + E;

    float* xw  = (float*)d_ws;                          // N*W
    float* acc = xw + (size_t)N * WDIM;                 // N*W
    int2*  e_pk = (int2*)(acc + (size_t)N * WDIM);      // E int2
    int*   cnt = (int*)(e_pk + E);                      // N
    int*   scn = cnt + N;                               // N
    int*   row_start = scn + N;                         // N
    int*   cursor = row_start + N;                      // N
    float* dinv = (float*)(cursor + N);                 // N
    int*   bsum = (int*)(dinv + N);                     // 512
    int*   bscan = bsum + 512;                          // 512
    float* hbuf = xw;                                   // alias: xw dead after k_gather

    const int B = 256;
    const int NB = (N + 255) / 256;
    auto blocks = [](long long work, int cap) {
        long long b = (work + 255) / 256;
        return (int)(b < cap ? b : cap);
    };

    const int t_xw  = (N + 63) / 64;
    const int t_h   = (N + 127) / 128;
    const int t_out = (N + 63) / 64;

    k_zero<<<blocks(N, 2048), B, 0, stream>>>(cnt, N);
    k_hist<<<blocks(E, 2048), B, 0, stream>>>(dst, cnt, E);
    k_scan1<<<NB, B, 0, stream>>>(cnt, scn, bsum, N);
    k_scan2<<<1, 512, 0, stream>>>(bsum, bscan, NB);
    k_scan3<<<blocks(N, 2048), B, 0, stream>>>(cnt, scn, bscan, row_start, cursor, dinv, N);
    k_fill<<<blocks(E, 2048), B, 0, stream>>>(src, dst, dinv, cursor, e_pk, E);
    k_xw<<<640, 320, 0, stream>>>(x, gw, xw, N, t_xw);
    k_gather<<<(N * 64 + B - 1) / B, B, 0, stream>>>(e_pk, row_start, cnt, xw, dinv, gb, acc, N);
    k_h<<<512, 384, 0, stream>>>(acc, w1, b1, hbuf, N, t_h);
    k_out<<<640, 320, 0, stream>>>(hbuf, w2, b2, out, N, t_out);
}

// Round 4
// 520.150 us; speedup vs baseline: 3.0499x; 1.1159x over previous
//
#include <hip/hip_runtime.h>
#include <hip/hip_bf16.h>

#define WDIM 100
#define HDIM 60

// ---------------- zero int counters ----------------
__global__ __launch_bounds__(256) void k_zero(int* __restrict__ cnt, int N) {
    int i = blockIdx.x * blockDim.x + threadIdx.x;
    int stride = gridDim.x * blockDim.x;
    for (int idx = i; idx < N; idx += stride) cnt[idx] = 0;
}

// ---------------- histogram of dst ----------------
__global__ __launch_bounds__(256) void k_hist(const int* __restrict__ dst,
                                              int* __restrict__ cnt, int E) {
    int i = blockIdx.x * blockDim.x + threadIdx.x;
    int stride = gridDim.x * blockDim.x;
    for (int e = i; e < E; e += stride)
        atomicAdd(&cnt[dst[e]], 1);
}

// ---------------- scan step 1 ----------------
__global__ __launch_bounds__(256) void k_scan1(const int* __restrict__ cnt,
                                               int* __restrict__ scn,
                                               int* __restrict__ bsum, int N) {
    __shared__ int tmp[256];
    int idx = blockIdx.x * 256 + threadIdx.x;
    int v = (idx < N) ? cnt[idx] : 0;
    tmp[threadIdx.x] = v;
    __syncthreads();
    for (int off = 1; off < 256; off <<= 1) {
        int t = (threadIdx.x >= off) ? tmp[threadIdx.x - off] : 0;
        __syncthreads();
        tmp[threadIdx.x] += t;
        __syncthreads();
    }
    if (idx < N) scn[idx] = tmp[threadIdx.x];
    if (threadIdx.x == 255) bsum[blockIdx.x] = tmp[255];
}

// ---------------- scan step 2 ----------------
__global__ __launch_bounds__(512) void k_scan2(const int* __restrict__ bsum,
                                               int* __restrict__ bscan, int NB) {
    __shared__ int tmp[512];
    int orig = (threadIdx.x < NB) ? bsum[threadIdx.x] : 0;
    tmp[threadIdx.x] = orig;
    __syncthreads();
    for (int off = 1; off < 512; off <<= 1) {
        int t = (threadIdx.x >= off) ? tmp[threadIdx.x - off] : 0;
        __syncthreads();
        tmp[threadIdx.x] += t;
        __syncthreads();
    }
    if (threadIdx.x < NB) bscan[threadIdx.x] = tmp[threadIdx.x] - orig;
}

// ---------------- scan step 3 ----------------
__global__ __launch_bounds__(256) void k_scan3(const int* __restrict__ cnt,
                                               const int* __restrict__ scn,
                                               const int* __restrict__ bscan,
                                               int* __restrict__ row_start,
                                               int* __restrict__ cursor,
                                               float* __restrict__ dinv, int N) {
    int i = blockIdx.x * blockDim.x + threadIdx.x;
    int stride = gridDim.x * blockDim.x;
    for (int idx = i; idx < N; idx += stride) {
        int c = cnt[idx];
        int ex = scn[idx] - c + bscan[idx >> 8];
        row_start[idx] = ex;
        cursor[idx] = ex;
        dinv[idx] = rsqrtf((float)(c + 1));
    }
}

// ---------------- fill CSR edge list ----------------
__global__ __launch_bounds__(256) void k_fill(const int* __restrict__ src,
                                              const int* __restrict__ dst,
                                              const float* __restrict__ dinv,
                                              int* __restrict__ cursor,
                                              int2* __restrict__ e_pk, int E) {
    int i = blockIdx.x * blockDim.x + threadIdx.x;
    int stride = gridDim.x * blockDim.x;
    for (int e = i; e < E; e += stride) {
        int s = src[e], d = dst[e];
        float nrm = dinv[s] * dinv[d];
        int pos = atomicAdd(&cursor[d], 1);
        e_pk[pos] = make_int2(s, __float_as_int(nrm));
    }
}

// ================= GEMM 1: xw = x @ gcn_w^T (writes fp32 + bf16 copies) ====
__global__ __launch_bounds__(320) void k_xw(const float* __restrict__ x,
                                            const float* __restrict__ gw,
                                            float* __restrict__ xw,
                                            unsigned short* __restrict__ xwh,
                                            int N, int ntiles) {
    __shared__ float wst[WDIM][104];   // [k][j]
    __shared__ float xs[WDIM][68];     // [k][n]
    for (int t = threadIdx.x; t < WDIM * WDIM; t += 320) {
        int j = t / WDIM, k = t - j * WDIM;
        wst[k][j] = gw[t];
    }
    const int jg = threadIdx.x % 20;
    const int ng = threadIdx.x / 20;
    for (int tile = blockIdx.x; tile < ntiles; tile += gridDim.x) {
        int n0 = tile * 64;
        __syncthreads();
        for (int t = threadIdx.x; t < 64 * WDIM; t += 320) {
            int n = t / WDIM, k = t - n * WDIM;
            int gn = n0 + n;
            xs[k][n] = (gn < N) ? x[(size_t)gn * WDIM + k] : 0.0f;
        }
        __syncthreads();
        float a[4][5];
#pragma unroll
        for (int i = 0; i < 4; ++i)
#pragma unroll
            for (int j = 0; j < 5; ++j) a[i][j] = 0.0f;
#pragma unroll 2
        for (int k = 0; k < WDIM; ++k) {
            float4 xv = *(const float4*)&xs[k][4 * ng];
            float w0 = wst[k][5 * jg + 0];
            float w1 = wst[k][5 * jg + 1];
            float w2 = wst[k][5 * jg + 2];
            float w3 = wst[k][5 * jg + 3];
            float w4 = wst[k][5 * jg + 4];
#pragma unroll
            for (int nn = 0; nn < 4; ++nn) {
                float xvv = (&xv.x)[nn];
                a[nn][0] = fmaf(xvv, w0, a[nn][0]);
                a[nn][1] = fmaf(xvv, w1, a[nn][1]);
                a[nn][2] = fmaf(xvv, w2, a[nn][2]);
                a[nn][3] = fmaf(xvv, w3, a[nn][3]);
                a[nn][4] = fmaf(xvv, w4, a[nn][4]);
            }
        }
#pragma unroll
        for (int nn = 0; nn < 4; ++nn) {
            int gn = n0 + 4 * ng + nn;
            if (gn < N) {
                float* __restrict__ o = xw + (size_t)gn * WDIM + 5 * jg;
                unsigned short* __restrict__ oh = xwh + (size_t)gn * WDIM + 5 * jg;
#pragma unroll
                for (int jj = 0; jj < 5; ++jj) {
                    o[jj] = a[nn][jj];
                    oh[jj] = __bfloat16_as_ushort(__float2bfloat16(a[nn][jj]));
                }
            }
        }
    }
}

// ---------------- pull-gather (bf16 rows): wave/node, lanes 0..49 x 2 feats --
__global__ __launch_bounds__(256) void k_gather(const int2* __restrict__ e_pk,
                                                const int* __restrict__ row_start,
                                                const int* __restrict__ cnt,
                                                const unsigned int* __restrict__ xwh,
                                                const float* __restrict__ xw,
                                                const float* __restrict__ dinv,
                                                const float* __restrict__ gb,
                                                float* __restrict__ acc, int N) {
    int wid = (blockIdx.x * blockDim.x + threadIdx.x) >> 6;
    int lane = threadIdx.x & 63;
    if (wid >= N || lane >= 50) return;
    int beg = row_start[wid];
    int num = cnt[wid];
    float sa0 = 0.0f, sa1 = 0.0f, sb0 = 0.0f, sb1 = 0.0f;
    int k = 0;
    for (; k + 2 <= num; k += 2) {
        int2 e0 = e_pk[beg + k];
        int2 e1 = e_pk[beg + k + 1];
        unsigned int u0 = xwh[(size_t)e0.x * 50 + lane];
        unsigned int u1 = xwh[(size_t)e1.x * 50 + lane];
        float n0 = __int_as_float(e0.y);
        float n1 = __int_as_float(e1.y);
        sa0 = fmaf(__uint_as_float(u0 << 16), n0, sa0);
        sa1 = fmaf(__uint_as_float(u0 & 0xffff0000u), n0, sa1);
        sb0 = fmaf(__uint_as_float(u1 << 16), n1, sb0);
        sb1 = fmaf(__uint_as_float(u1 & 0xffff0000u), n1, sb1);
    }
    if (k < num) {
        int2 e0 = e_pk[beg + k];
        unsigned int u0 = xwh[(size_t)e0.x * 50 + lane];
        float n0 = __int_as_float(e0.y);
        sa0 = fmaf(__uint_as_float(u0 << 16), n0, sa0);
        sa1 = fmaf(__uint_as_float(u0 & 0xffff0000u), n0, sa1);
    }
    float s0 = sa0 + sb0;
    float s1 = sa1 + sb1;
    float di = dinv[wid];
    float d2 = di * di;
    float2 xn = *(const float2*)(xw + (size_t)wid * WDIM + 2 * lane);
    float2 gbv = *(const float2*)(gb + 2 * lane);
    float v0 = fmaf(xn.x, d2, s0) + gbv.x;
    float v1 = fmaf(xn.y, d2, s1) + gbv.y;
    *(float2*)(acc + (size_t)wid * WDIM + 2 * lane) =
        make_float2(fmaxf(v0, 0.0f), fmaxf(v1, 0.0f));
}

// ================= GEMM 2: h = tanh(acc @ w1^T + b1) =================
__global__ __launch_bounds__(384) void k_h(const float* __restrict__ acc,
                                           const float* __restrict__ w1,
                                           const float* __restrict__ b1,
                                           float* __restrict__ h,
                                           int N, int ntiles) {
    __shared__ float wst[WDIM][64];
    __shared__ float xs[WDIM][132];
    for (int t = threadIdx.x; t < HDIM * WDIM; t += 384) {
        int j = t / WDIM, k = t - j * WDIM;
        wst[k][j] = w1[t];
    }
    const int jg = threadIdx.x % 12;
    const int ng = threadIdx.x / 12;
    float b[5];
#pragma unroll
    for (int jj = 0; jj < 5; ++jj) b[jj] = b1[5 * jg + jj];
    for (int tile = blockIdx.x; tile < ntiles; tile += gridDim.x) {
        int n0 = tile * 128;
        __syncthreads();
        for (int t = threadIdx.x; t < 128 * WDIM; t += 384) {
            int n = t / WDIM, k = t - n * WDIM;
            int gn = n0 + n;
            xs[k][n] = (gn < N) ? acc[(size_t)gn * WDIM + k] : 0.0f;
        }
        __syncthreads();
        float a[4][5];
#pragma unroll
        for (int i = 0; i < 4; ++i)
#pragma unroll
            for (int j = 0; j < 5; ++j) a[i][j] = b[j];
#pragma unroll 2
        for (int k = 0; k < WDIM; ++k) {
            float4 xv = *(const float4*)&xs[k][4 * ng];
            float w0 = wst[k][5 * jg + 0];
            float w1v = wst[k][5 * jg + 1];
            float w2 = wst[k][5 * jg + 2];
            float w3 = wst[k][5 * jg + 3];
            float w4 = wst[k][5 * jg + 4];
#pragma unroll
            for (int nn = 0; nn < 4; ++nn) {
                float xvv = (&xv.x)[nn];
                a[nn][0] = fmaf(xvv, w0, a[nn][0]);
                a[nn][1] = fmaf(xvv, w1v, a[nn][1]);
                a[nn][2] = fmaf(xvv, w2, a[nn][2]);
                a[nn][3] = fmaf(xvv, w3, a[nn][3]);
                a[nn][4] = fmaf(xvv, w4, a[nn][4]);
            }
        }
#pragma unroll
        for (int nn = 0; nn < 4; ++nn) {
            int gn = n0 + 4 * ng + nn;
            if (gn < N) {
                float* __restrict__ o = h + (size_t)gn * HDIM + 5 * jg;
#pragma unroll
                for (int jj = 0; jj < 5; ++jj) o[jj] = tanhf(a[nn][jj]);
            }
        }
    }
}

// ================= GEMM 3: out = tanh(h @ w2^T + b2) =================
__global__ __launch_bounds__(320) void k_out(const float* __restrict__ h,
                                             const float* __restrict__ w2,
                                             const float* __restrict__ b2,
                                             float* __restrict__ out,
                                             int N, int ntiles) {
    __shared__ float wst[HDIM][104];
    __shared__ float xs[HDIM][68];
    for (int t = threadIdx.x; t < WDIM * HDIM; t += 320) {
        int j = t / HDIM, k = t - j * HDIM;
        wst[k][j] = w2[t];
    }
    const int jg = threadIdx.x % 20;
    const int ng = threadIdx.x / 20;
    float b[5];
#pragma unroll
    for (int jj = 0; jj < 5; ++jj) b[jj] = b2[5 * jg + jj];
    for (int tile = blockIdx.x; tile < ntiles; tile += gridDim.x) {
        int n0 = tile * 64;
        __syncthreads();
        for (int t = threadIdx.x; t < 64 * HDIM; t += 320) {
            int n = t / HDIM, k = t - n * HDIM;
            int gn = n0 + n;
            xs[k][n] = (gn < N) ? h[(size_t)gn * HDIM + k] : 0.0f;
        }
        __syncthreads();
        float a[4][5];
#pragma unroll
        for (int i = 0; i < 4; ++i)
#pragma unroll
            for (int j = 0; j < 5; ++j) a[i][j] = b[j];
#pragma unroll 2
        for (int k = 0; k < HDIM; ++k) {
            float4 xv = *(const float4*)&xs[k][4 * ng];
            float w0 = wst[k][5 * jg + 0];
            float w1v = wst[k][5 * jg + 1];
            float w2v = wst[k][5 * jg + 2];
            float w3 = wst[k][5 * jg + 3];
            float w4 = wst[k][5 * jg + 4];
#pragma unroll
            for (int nn = 0; nn < 4; ++nn) {
                float xvv = (&xv.x)[nn];
                a[nn][0] = fmaf(xvv, w0, a[nn][0]);
                a[nn][1] = fmaf(xvv, w1v, a[nn][1]);
                a[nn][2] = fmaf(xvv, w2v, a[nn][2]);
                a[nn][3] = fmaf(xvv, w3, a[nn][3]);
                a[nn][4] = fmaf(xvv, w4, a[nn][4]);
            }
        }
#pragma unroll
        for (int nn = 0; nn < 4; ++nn) {
            int gn = n0 + 4 * ng + nn;
            if (gn < N) {
                float* __restrict__ o = out + (size_t)gn * WDIM + 5 * jg;
#pragma unroll
                for (int jj = 0; jj < 5; ++jj) o[jj] = tanhf(a[nn][jj]);
            }
        }
    }
}

extern "C" void kernel_launch(void* const* d_in, const int* in_sizes, int n_in,
                              void* d_out, int out_size, void* d_ws, size_t ws_size,
                              hipStream_t stream) {
    const float* x   = (const float*)d_in[0];
    const int*   ei  = (const int*)d_in[1];
    const float* gw  = (const float*)d_in[2];
    const float* gb  = (const float*)d_in[3];
    const float* w1  = (const float*)d_in[4];
    const float* b1  = (const float*)d_in[5];
    const float* w2  = (const float*)d_in[6];
    const float* b2  = (const float*)d_in[7];
    float* out = (float*)d_out;

    const int W = in_sizes[3];          // 100
    const int N = in_sizes[0] / W;      // 100000
    const int E = in_sizes[1] / 2;      // 1600000

    const int* src = ei;
    const int* dst = ei + E;

    float* xw  = (float*)d_ws;                          // N*W f32
    float* acc = xw + (size_t)N * WDIM;                 // N*W f32
    int2*  e_pk = (int2*)(acc + (size_t)N * WDIM);      // E int2
    int*   cnt = (int*)(e_pk + E);                      // N
    int*   scn = cnt + N;                               // N
    int*   row_start = scn + N;                         // N
    int*   cursor = row_start + N;                      // N
    float* dinv = (float*)(cursor + N);                 // N
    int*   bsum = (int*)(dinv + N);                     // 512
    int*   bscan = bsum + 512;                          // 512
    unsigned short* xwh = (unsigned short*)(bscan + 512); // N*W bf16 (20 MB)
    float* hbuf = xw;                                   // alias: xw dead after k_gather

    const int B = 256;
    const int NB = (N + 255) / 256;
    auto blocks = [](long long work, int cap) {
        long long b = (work + 255) / 256;
        return (int)(b < cap ? b : cap);
    };

    const int t_xw  = (N + 63) / 64;
    const int t_h   = (N + 127) / 128;
    const int t_out = (N + 63) / 64;

    k_zero<<<blocks(N, 2048), B, 0, stream>>>(cnt, N);
    k_hist<<<blocks(E, 2048), B, 0, stream>>>(dst, cnt, E);
    k_scan1<<<NB, B, 0, stream>>>(cnt, scn, bsum, N);
    k_scan2<<<1, 512, 0, stream>>>(bsum, bscan, NB);
    k_scan3<<<blocks(N, 2048), B, 0, stream>>>(cnt, scn, bscan, row_start, cursor, dinv, N);
    k_fill<<<blocks(E, 2048), B, 0, stream>>>(src, dst, dinv, cursor, e_pk, E);
    k_xw<<<640, 320, 0, stream>>>(x, gw, xw, xwh, N, t_xw);
    k_gather<<<(N * 64 + B - 1) / B, B, 0, stream>>>(e_pk, row_start, cnt,
                                                     (const unsigned int*)xwh, xw,
                                                     dinv, gb, acc, N);
    k_h<<<512, 384, 0, stream>>>(acc, w1, b1, hbuf, N, t_h);
    k_out<<<640, 320, 0, stream>>>(hbuf, w2, b2, out, N, t_out);
}

// Round 5
// 408.710 us; speedup vs baseline: 3.8815x; 1.2727x over previous
//
#include <hip/hip_runtime.h>
#include <hip/hip_bf16.h>

#define WDIM 100
#define HDIM 60

typedef short bf16x8 __attribute__((ext_vector_type(8)));
typedef float f32x4 __attribute__((ext_vector_type(4)));

__device__ inline unsigned short bf_hi_u(float v) {
    return __bfloat16_as_ushort(__float2bfloat16(v));
}
__device__ inline float bf_f(unsigned short u) {
    return __uint_as_float(((unsigned int)u) << 16);
}
// split v0,v1 into bf16 hi/lo packed words
__device__ inline void split2(float v0, float v1, unsigned int& wh, unsigned int& wl) {
    unsigned short h0 = bf_hi_u(v0), h1 = bf_hi_u(v1);
    unsigned short l0 = bf_hi_u(v0 - bf_f(h0)), l1 = bf_hi_u(v1 - bf_f(h1));
    wh = (unsigned int)h0 | ((unsigned int)h1 << 16);
    wl = (unsigned int)l0 | ((unsigned int)l1 << 16);
}

// ---------------- zero int counters ----------------
__global__ __launch_bounds__(256) void k_zero(int* __restrict__ cnt, int N) {
    int i = blockIdx.x * blockDim.x + threadIdx.x;
    int stride = gridDim.x * blockDim.x;
    for (int idx = i; idx < N; idx += stride) cnt[idx] = 0;
}

// ---------------- histogram of dst ----------------
__global__ __launch_bounds__(256) void k_hist(const int* __restrict__ dst,
                                              int* __restrict__ cnt, int E) {
    int i = blockIdx.x * blockDim.x + threadIdx.x;
    int stride = gridDim.x * blockDim.x;
    for (int e = i; e < E; e += stride)
        atomicAdd(&cnt[dst[e]], 1);
}

// ---------------- scan step 1 ----------------
__global__ __launch_bounds__(256) void k_scan1(const int* __restrict__ cnt,
                                               int* __restrict__ scn,
                                               int* __restrict__ bsum, int N) {
    __shared__ int tmp[256];
    int idx = blockIdx.x * 256 + threadIdx.x;
    int v = (idx < N) ? cnt[idx] : 0;
    tmp[threadIdx.x] = v;
    __syncthreads();
    for (int off = 1; off < 256; off <<= 1) {
        int t = (threadIdx.x >= off) ? tmp[threadIdx.x - off] : 0;
        __syncthreads();
        tmp[threadIdx.x] += t;
        __syncthreads();
    }
    if (idx < N) scn[idx] = tmp[threadIdx.x];
    if (threadIdx.x == 255) bsum[blockIdx.x] = tmp[255];
}

// ---------------- scan step 2 ----------------
__global__ __launch_bounds__(512) void k_scan2(const int* __restrict__ bsum,
                                               int* __restrict__ bscan, int NB) {
    __shared__ int tmp[512];
    int orig = (threadIdx.x < NB) ? bsum[threadIdx.x] : 0;
    tmp[threadIdx.x] = orig;
    __syncthreads();
    for (int off = 1; off < 512; off <<= 1) {
        int t = (threadIdx.x >= off) ? tmp[threadIdx.x - off] : 0;
        __syncthreads();
        tmp[threadIdx.x] += t;
        __syncthreads();
    }
    if (threadIdx.x < NB) bscan[threadIdx.x] = tmp[threadIdx.x] - orig;
}

// ---------------- scan step 3 ----------------
__global__ __launch_bounds__(256) void k_scan3(const int* __restrict__ cnt,
                                               const int* __restrict__ scn,
                                               const int* __restrict__ bscan,
                                               int* __restrict__ row_start,
                                               int* __restrict__ cursor,
                                               float* __restrict__ dinv, int N) {
    int i = blockIdx.x * blockDim.x + threadIdx.x;
    int stride = gridDim.x * blockDim.x;
    for (int idx = i; idx < N; idx += stride) {
        int c = cnt[idx];
        int ex = scn[idx] - c + bscan[idx >> 8];
        row_start[idx] = ex;
        cursor[idx] = ex;
        dinv[idx] = rsqrtf((float)(c + 1));
    }
}

// ---------------- fill CSR edge list ----------------
__global__ __launch_bounds__(256) void k_fill(const int* __restrict__ src,
                                              const int* __restrict__ dst,
                                              const float* __restrict__ dinv,
                                              int* __restrict__ cursor,
                                              int2* __restrict__ e_pk, int E) {
    int i = blockIdx.x * blockDim.x + threadIdx.x;
    int stride = gridDim.x * blockDim.x;
    for (int e = i; e < E; e += stride) {
        int s = src[e], d = dst[e];
        float nrm = dinv[s] * dinv[d];
        int pos = atomicAdd(&cursor[d], 1);
        e_pk[pos] = make_int2(s, __float_as_int(nrm));
    }
}

// ============ MFMA GEMM 1: xwh(bf16) = x @ gcn_w^T ============
// 64-node tile/block, 4 waves x 16 rows, cols padded 112, K padded 128.
// LDS: wlds [112 rows j][128 k] bf16 swizzled; xlds hi/lo [64][128] swizzled;
// clds (bf16 [64][112]) aliases xlds after fragment preload.
__global__ __launch_bounds__(256) void k_xw(const float* __restrict__ x,
                                            const float* __restrict__ gw,
                                            unsigned int* __restrict__ xwh, int N) {
    __shared__ char wlds[112 * 256];        // 28672 B
    __shared__ char xlds[2 * 64 * 256];     // 32768 B
    const int tid = threadIdx.x;
    const int n0 = blockIdx.x * 64;

    // stage weights: B[k][j] = gw[j*100+k] -> row j of gw
    for (int w = tid; w < 112 * 64; w += 256) {
        int j = w >> 6, kp = w & 63;
        unsigned int val = 0;
        if (j < 100 && kp < 50) {
            float v0 = gw[j * 100 + 2 * kp];
            float v1 = gw[j * 100 + 2 * kp + 1];
            val = (unsigned int)bf_hi_u(v0) | ((unsigned int)bf_hi_u(v1) << 16);
        }
        *(unsigned int*)&wlds[j * 256 + ((kp * 4) ^ ((j & 7) << 4))] = val;
    }
    // stage x hi/lo
    char* xhi = xlds;
    char* xlo = xlds + 64 * 256;
    for (int w = tid; w < 64 * 64; w += 256) {
        int n = w >> 6, kp = w & 63;
        int gn = n0 + n;
        unsigned int vh = 0, vl = 0;
        if (gn < N && kp < 50) {
            float2 v = *(const float2*)&x[(size_t)gn * 100 + 2 * kp];
            split2(v.x, v.y, vh, vl);
        }
        int off = n * 256 + ((kp * 4) ^ ((n & 7) << 4));
        *(unsigned int*)&xhi[off] = vh;
        *(unsigned int*)&xlo[off] = vl;
    }
    __syncthreads();

    const int wv = tid >> 6, l = tid & 63;
    const int arow = wv * 16 + (l & 15);
    const int koff = (l >> 4) * 8;
    bf16x8 ah[4], al[4];
#pragma unroll
    for (int kt = 0; kt < 4; ++kt) {
        int off = arow * 256 + (((kt * 32 + koff) * 2) ^ ((arow & 7) << 4));
        ah[kt] = *(const bf16x8*)&xhi[off];
        al[kt] = *(const bf16x8*)&xlo[off];
    }
    __syncthreads();   // xlds now dead -> reuse as clds

    char* clds = xlds;                       // [64][112] bf16, stride 224 B
    const int cl = l & 15;
#pragma unroll
    for (int jt = 0; jt < 7; ++jt) {
        f32x4 acc = {0.f, 0.f, 0.f, 0.f};
#pragma unroll
        for (int kt = 0; kt < 4; ++kt) {
            int brow = jt * 16 + cl;
            int off = brow * 256 + (((kt * 32 + koff) * 2) ^ ((brow & 7) << 4));
            bf16x8 b = *(const bf16x8*)&wlds[off];
            acc = __builtin_amdgcn_mfma_f32_16x16x32_bf16(ah[kt], b, acc, 0, 0, 0);
            acc = __builtin_amdgcn_mfma_f32_16x16x32_bf16(al[kt], b, acc, 0, 0, 0);
        }
        int node = wv * 16 + (l >> 4) * 4;
        int col = jt * 16 + cl;
#pragma unroll
        for (int r = 0; r < 4; ++r)
            *(unsigned short*)&clds[(node + r) * 224 + col * 2] = bf_hi_u(acc[r]);
    }
    __syncthreads();
    for (int w = tid; w < 64 * 50; w += 256) {
        int n = w / 50, c = w - n * 50;
        int gn = n0 + n;
        if (gn < N)
            xwh[(size_t)gn * 50 + c] = *(unsigned int*)&clds[n * 224 + c * 4];
    }
}

// ---------------- pull-gather: wave/node, bf16 rows, writes relu hi/lo ------
__global__ __launch_bounds__(256) void k_gather(const int2* __restrict__ e_pk,
                                                const int* __restrict__ row_start,
                                                const int* __restrict__ cnt,
                                                const unsigned int* __restrict__ xwh,
                                                const float* __restrict__ dinv,
                                                const float* __restrict__ gb,
                                                unsigned int* __restrict__ acch,
                                                unsigned int* __restrict__ accl, int N) {
    int wid = (blockIdx.x * blockDim.x + threadIdx.x) >> 6;
    int lane = threadIdx.x & 63;
    if (wid >= N || lane >= 50) return;
    int beg = row_start[wid];
    int num = cnt[wid];
    float sa0 = 0.0f, sa1 = 0.0f, sb0 = 0.0f, sb1 = 0.0f;
    int k = 0;
    for (; k + 2 <= num; k += 2) {
        int2 e0 = e_pk[beg + k];
        int2 e1 = e_pk[beg + k + 1];
        unsigned int u0 = xwh[(size_t)e0.x * 50 + lane];
        unsigned int u1 = xwh[(size_t)e1.x * 50 + lane];
        float n0 = __int_as_float(e0.y);
        float n1 = __int_as_float(e1.y);
        sa0 = fmaf(__uint_as_float(u0 << 16), n0, sa0);
        sa1 = fmaf(__uint_as_float(u0 & 0xffff0000u), n0, sa1);
        sb0 = fmaf(__uint_as_float(u1 << 16), n1, sb0);
        sb1 = fmaf(__uint_as_float(u1 & 0xffff0000u), n1, sb1);
    }
    if (k < num) {
        int2 e0 = e_pk[beg + k];
        unsigned int u0 = xwh[(size_t)e0.x * 50 + lane];
        float n0 = __int_as_float(e0.y);
        sa0 = fmaf(__uint_as_float(u0 << 16), n0, sa0);
        sa1 = fmaf(__uint_as_float(u0 & 0xffff0000u), n0, sa1);
    }
    float s0 = sa0 + sb0;
    float s1 = sa1 + sb1;
    float di = dinv[wid];
    float d2 = di * di;
    unsigned int uself = xwh[(size_t)wid * 50 + lane];
    float x0 = __uint_as_float(uself << 16);
    float x1 = __uint_as_float(uself & 0xffff0000u);
    float2 gbv = *(const float2*)(gb + 2 * lane);
    float v0 = fmaxf(fmaf(x0, d2, s0) + gbv.x, 0.0f);
    float v1 = fmaxf(fmaf(x1, d2, s1) + gbv.y, 0.0f);
    unsigned int wh, wl;
    split2(v0, v1, wh, wl);
    acch[(size_t)wid * 50 + lane] = wh;
    accl[(size_t)wid * 50 + lane] = wl;
}

// ============ MFMA GEMM 2: h(hi/lo bf16) = tanh(acc @ w1^T + b1) ============
// cols padded 64, K padded 128.
__global__ __launch_bounds__(256) void k_h(const unsigned int* __restrict__ acch,
                                           const unsigned int* __restrict__ accl,
                                           const float* __restrict__ w1,
                                           const float* __restrict__ b1,
                                           unsigned int* __restrict__ hh,
                                           unsigned int* __restrict__ hl, int N) {
    __shared__ char wlds[64 * 256];         // 16384 B
    __shared__ char xlds[2 * 64 * 256];     // 32768 B ; clds f32 [64][64] aliases
    const int tid = threadIdx.x;
    const int n0 = blockIdx.x * 64;

    for (int w = tid; w < 64 * 64; w += 256) {
        int j = w >> 6, kp = w & 63;
        unsigned int val = 0;
        if (j < 60 && kp < 50) {
            float v0 = w1[j * 100 + 2 * kp];
            float v1 = w1[j * 100 + 2 * kp + 1];
            val = (unsigned int)bf_hi_u(v0) | ((unsigned int)bf_hi_u(v1) << 16);
        }
        *(unsigned int*)&wlds[j * 256 + ((kp * 4) ^ ((j & 7) << 4))] = val;
    }
    char* xhi = xlds;
    char* xlo = xlds + 64 * 256;
    for (int w = tid; w < 64 * 64; w += 256) {
        int n = w >> 6, kp = w & 63;
        int gn = n0 + n;
        unsigned int vh = 0, vl = 0;
        if (gn < N && kp < 50) {
            vh = acch[(size_t)gn * 50 + kp];
            vl = accl[(size_t)gn * 50 + kp];
        }
        int off = n * 256 + ((kp * 4) ^ ((n & 7) << 4));
        *(unsigned int*)&xhi[off] = vh;
        *(unsigned int*)&xlo[off] = vl;
    }
    __syncthreads();

    const int wv = tid >> 6, l = tid & 63;
    const int arow = wv * 16 + (l & 15);
    const int koff = (l >> 4) * 8;
    bf16x8 ah[4], al[4];
#pragma unroll
    for (int kt = 0; kt < 4; ++kt) {
        int off = arow * 256 + (((kt * 32 + koff) * 2) ^ ((arow & 7) << 4));
        ah[kt] = *(const bf16x8*)&xhi[off];
        al[kt] = *(const bf16x8*)&xlo[off];
    }
    __syncthreads();

    char* clds = xlds;                      // f32 [64][64], stride 256 B
    const int cl = l & 15;
#pragma unroll
    for (int jt = 0; jt < 4; ++jt) {
        f32x4 acc = {0.f, 0.f, 0.f, 0.f};
#pragma unroll
        for (int kt = 0; kt < 4; ++kt) {
            int brow = jt * 16 + cl;
            int off = brow * 256 + (((kt * 32 + koff) * 2) ^ ((brow & 7) << 4));
            bf16x8 b = *(const bf16x8*)&wlds[off];
            acc = __builtin_amdgcn_mfma_f32_16x16x32_bf16(ah[kt], b, acc, 0, 0, 0);
            acc = __builtin_amdgcn_mfma_f32_16x16x32_bf16(al[kt], b, acc, 0, 0, 0);
        }
        int node = wv * 16 + (l >> 4) * 4;
        int col = jt * 16 + cl;
        float bias = (col < 60) ? b1[col] : 0.0f;
#pragma unroll
        for (int r = 0; r < 4; ++r)
            *(float*)&clds[(node + r) * 256 + col * 4] = tanhf(acc[r] + bias);
    }
    __syncthreads();
    for (int w = tid; w < 64 * 30; w += 256) {
        int n = w / 30, c = w - n * 30;
        int gn = n0 + n;
        if (gn < N) {
            float2 v = *(const float2*)&clds[n * 256 + c * 8];
            unsigned int wh, wl;
            split2(v.x, v.y, wh, wl);
            hh[(size_t)gn * 30 + c] = wh;
            hl[(size_t)gn * 30 + c] = wl;
        }
    }
}

// ============ MFMA GEMM 3: out(f32) = tanh(h @ w2^T + b2) ============
// cols padded 112, K padded 64 (row stride 128 B).
__global__ __launch_bounds__(256) void k_out(const unsigned int* __restrict__ hh,
                                             const unsigned int* __restrict__ hl,
                                             const float* __restrict__ w2,
                                             const float* __restrict__ b2,
                                             float* __restrict__ out, int N) {
    __shared__ char wlds[112 * 128];        // 14336 B
    __shared__ char xbuf[64 * 112 * 4];     // 28672 B: xlds hi/lo in first 16384, clds f32 aliases
    const int tid = threadIdx.x;
    const int n0 = blockIdx.x * 64;

    for (int w = tid; w < 112 * 32; w += 256) {
        int j = w >> 5, kp = w & 31;
        unsigned int val = 0;
        if (j < 100 && kp < 30) {
            float v0 = w2[j * 60 + 2 * kp];
            float v1 = w2[j * 60 + 2 * kp + 1];
            val = (unsigned int)bf_hi_u(v0) | ((unsigned int)bf_hi_u(v1) << 16);
        }
        *(unsigned int*)&wlds[j * 128 + ((kp * 4) ^ ((j & 7) << 4))] = val;
    }
    char* xhi = xbuf;
    char* xlo = xbuf + 64 * 128;
    for (int w = tid; w < 64 * 32; w += 256) {
        int n = w >> 5, kp = w & 31;
        int gn = n0 + n;
        unsigned int vh = 0, vl = 0;
        if (gn < N && kp < 30) {
            vh = hh[(size_t)gn * 30 + kp];
            vl = hl[(size_t)gn * 30 + kp];
        }
        int off = n * 128 + ((kp * 4) ^ ((n & 7) << 4));
        *(unsigned int*)&xhi[off] = vh;
        *(unsigned int*)&xlo[off] = vl;
    }
    __syncthreads();

    const int wv = tid >> 6, l = tid & 63;
    const int arow = wv * 16 + (l & 15);
    const int koff = (l >> 4) * 8;
    bf16x8 ah[2], al[2];
#pragma unroll
    for (int kt = 0; kt < 2; ++kt) {
        int off = arow * 128 + (((kt * 32 + koff) * 2) ^ ((arow & 7) << 4));
        ah[kt] = *(const bf16x8*)&xhi[off];
        al[kt] = *(const bf16x8*)&xlo[off];
    }
    __syncthreads();

    char* clds = xbuf;                      // f32 [64][112], stride 448 B
    const int cl = l & 15;
#pragma unroll
    for (int jt = 0; jt < 7; ++jt) {
        f32x4 acc = {0.f, 0.f, 0.f, 0.f};
#pragma unroll
        for (int kt = 0; kt < 2; ++kt) {
            int brow = jt * 16 + cl;
            int off = brow * 128 + (((kt * 32 + koff) * 2) ^ ((brow & 7) << 4));
            bf16x8 b = *(const bf16x8*)&wlds[off];
            acc = __builtin_amdgcn_mfma_f32_16x16x32_bf16(ah[kt], b, acc, 0, 0, 0);
            acc = __builtin_amdgcn_mfma_f32_16x16x32_bf16(al[kt], b, acc, 0, 0, 0);
        }
        int node = wv * 16 + (l >> 4) * 4;
        int col = jt * 16 + cl;
        float bias = (col < 100) ? b2[col] : 0.0f;
#pragma unroll
        for (int r = 0; r < 4; ++r)
            *(float*)&clds[(node + r) * 448 + col * 4] = tanhf(acc[r] + bias);
    }
    __syncthreads();
    for (int w = tid; w < 64 * 25; w += 256) {
        int n = w / 25, c4 = w - n * 25;
        int gn = n0 + n;
        if (gn < N)
            *(float4*)&out[(size_t)gn * 100 + c4 * 4] = *(const float4*)&clds[n * 448 + c4 * 16];
    }
}

extern "C" void kernel_launch(void* const* d_in, const int* in_sizes, int n_in,
                              void* d_out, int out_size, void* d_ws, size_t ws_size,
                              hipStream_t stream) {
    const float* x   = (const float*)d_in[0];
    const int*   ei  = (const int*)d_in[1];
    const float* gw  = (const float*)d_in[2];
    const float* gb  = (const float*)d_in[3];
    const float* w1  = (const float*)d_in[4];
    const float* b1  = (const float*)d_in[5];
    const float* w2  = (const float*)d_in[6];
    const float* b2  = (const float*)d_in[7];
    float* out = (float*)d_out;

    const int W = in_sizes[3];          // 100
    const int N = in_sizes[0] / W;      // 100000
    const int E = in_sizes[1] / 2;      // 1600000

    const int* src = ei;
    const int* dst = ei + E;

    // ---- workspace layout (4B words) ----
    unsigned int* xwh  = (unsigned int*)d_ws;           // N*50 (bf16 pairs)
    unsigned int* acch = xwh + (size_t)N * 50;          // N*50
    unsigned int* accl = acch + (size_t)N * 50;         // N*50
    unsigned int* hh   = accl + (size_t)N * 50;         // N*30
    unsigned int* hl   = hh + (size_t)N * 30;           // N*30
    int2*  e_pk = (int2*)(hl + (size_t)N * 30);         // E int2 (8B-aligned: offset 21e6 words)
    int*   cnt = (int*)(e_pk + E);                      // N
    int*   scn = cnt + N;                               // N
    int*   row_start = scn + N;                         // N
    int*   cursor = row_start + N;                      // N
    float* dinv = (float*)(cursor + N);                 // N
    int*   bsum = (int*)(dinv + N);                     // 512
    int*   bscan = bsum + 512;                          // 512

    const int B = 256;
    const int NB = (N + 255) / 256;
    const int NT = (N + 63) / 64;                       // 64-node tiles (1563)
    auto blocks = [](long long work, int cap) {
        long long b = (work + 255) / 256;
        return (int)(b < cap ? b : cap);
    };

    k_zero<<<blocks(N, 2048), B, 0, stream>>>(cnt, N);
    k_hist<<<blocks(E, 2048), B, 0, stream>>>(dst, cnt, E);
    k_scan1<<<NB, B, 0, stream>>>(cnt, scn, bsum, N);
    k_scan2<<<1, 512, 0, stream>>>(bsum, bscan, NB);
    k_scan3<<<blocks(N, 2048), B, 0, stream>>>(cnt, scn, bscan, row_start, cursor, dinv, N);
    k_fill<<<blocks(E, 2048), B, 0, stream>>>(src, dst, dinv, cursor, e_pk, E);
    k_xw<<<NT, B, 0, stream>>>(x, gw, xwh, N);
    k_gather<<<(N * 64 + B - 1) / B, B, 0, stream>>>(e_pk, row_start, cnt, xwh,
                                                     dinv, gb, acch, accl, N);
    k_h<<<NT, B, 0, stream>>>(acch, accl, w1, b1, hh, hl, N);
    k_out<<<NT, B, 0, stream>>>(hh, hl, w2, b2, out, N);
}